// Round 4
// baseline (273.188 us; speedup 1.0000x reference)
//
#include <hip/hip_runtime.h>

// Problem constants (from reference):
//   N = 64 (protein length), B = 32 (batch), L = 2N-1 = 127 (lattice side)
//   out = (B, L, L, L) float32 = 65,548,256 elems = 262,193,024 B (~262 MB)
//
// R2 evidence: dur_us(248) = harness poison fill (~164 us, out of our control)
//   + our zero kernel (~82 us @ 3.2 TB/s) + scatter (~2 us).
// Theory: zero kernel is L2 write-allocate bound; nontemporal (nt) stores +
// grid-stride at full occupancy should reach write-only ceiling (~45-60 us).
// R3 fix: __builtin_nontemporal_store needs a native vector type, not HIP float4.

typedef float vfloat4 __attribute__((ext_vector_type(4)));

constexpr int PN = 64;
constexpr int PB = 32;
constexpr int PL = 2 * PN - 1;  // 127
constexpr long long TOTAL_F  = (long long)PB * PL * PL * PL;  // 65,548,256 (div by 4)
constexpr long long TOTAL_V4 = TOTAL_F / 4;                   // 16,387,064 vfloat4s

constexpr int ZB = 256;      // block size
constexpr int ZG = 2048;     // 8 blocks/CU on 256 CUs -> full wave occupancy

__global__ __launch_bounds__(ZB) void lattice_zero_kernel(vfloat4* __restrict__ out) {
    const long long stride = (long long)ZG * ZB;
    const vfloat4 z = {0.f, 0.f, 0.f, 0.f};
    for (long long t = (long long)blockIdx.x * ZB + threadIdx.x; t < TOTAL_V4; t += stride) {
        __builtin_nontemporal_store(z, &out[t]);
    }
}

__global__ void lattice_scatter_kernel(const float* __restrict__ acids,
                                       const int*   __restrict__ idx,
                                       const int*   __restrict__ mask,
                                       float*       __restrict__ out) {
    int t = blockIdx.x * blockDim.x + threadIdx.x;   // 0 .. B*N-1
    if (t >= PB * PN) return;
    if (mask[t] == 0) return;        // masked-off acids scatter 0 -> no-op under add
    float v = acids[t];
    int b = t >> 6;                  // t / N  (N == 64)
    int i0 = idx[3 * t + 0] + (PN - 1);
    int i1 = idx[3 * t + 1] + (PN - 1);
    int i2 = idx[3 * t + 2] + (PN - 1);
    size_t off = ((((size_t)b * PL + i0) * PL) + i1) * PL + i2;
    atomicAdd(out + off, v);         // device-scope; handles index collisions
}

extern "C" void kernel_launch(void* const* d_in, const int* in_sizes, int n_in,
                              void* d_out, int out_size, void* d_ws, size_t ws_size,
                              hipStream_t stream) {
    const float* acids = (const float*)d_in[0];   // (B,N) f32
    const int*   idx   = (const int*)  d_in[1];   // (B,N,3) i32
    const int*   mask  = (const int*)  d_in[2];   // (B,N) bool -> i32 per harness
    float* out = (float*)d_out;

    // Zero the lattice with nontemporal float4 stores at full occupancy.
    lattice_zero_kernel<<<ZG, ZB, 0, stream>>>((vfloat4*)out);

    // Scatter-add the 2048 masked values (stream-ordered after the zero).
    constexpr int total = PB * PN;   // 2048
    lattice_scatter_kernel<<<(total + 255) / 256, 256, 0, stream>>>(acids, idx, mask, out);
}

// Round 5
// 255.371 us; speedup vs baseline: 1.0698x; 1.0698x over previous
//
#include <hip/hip_runtime.h>

// Problem constants (from reference):
//   N = 64 (protein length), B = 32 (batch), L = 2N-1 = 127 (lattice side)
//   out = (B, L, L, L) float32 = 65,548,256 elems = 262,193,024 B (~262 MB)
//
// Model (R1-R4): dur_us = harness poison (~165 us, fixed) + zero + scatter(~2).
//   R1 memset-node ~82 us, R2 1-store/thread kernel ~82 us (3.2 TB/s write),
//   R4 nt stores ~107 us (nt REGRESSES - bypasses L2 write combining).
// R5 experiment: 8 coalesced float4 stores per thread, 8002 blocks, no nt.
//   Tests whether 3.2 TB/s was launch/issue-bound or the HW write ceiling.

constexpr int PN = 64;
constexpr int PB = 32;
constexpr int PL = 2 * PN - 1;  // 127
constexpr long long TOTAL_F  = (long long)PB * PL * PL * PL;  // 65,548,256 (div by 4)
constexpr long long TOTAL_V4 = TOTAL_F / 4;                   // 16,387,064 float4s

constexpr int ZB  = 256;  // block size
constexpr int ZPT = 8;    // float4 stores per thread (block covers 32 KB)

__global__ __launch_bounds__(ZB) void lattice_zero_kernel(float4* __restrict__ out) {
    const long long base = (long long)blockIdx.x * (ZB * ZPT) + threadIdx.x;
    const float4 z = make_float4(0.f, 0.f, 0.f, 0.f);
#pragma unroll
    for (int k = 0; k < ZPT; ++k) {
        long long t = base + (long long)k * ZB;   // coalesced: wave covers 1KB/iter
        if (t < TOTAL_V4) out[t] = z;
    }
}

__global__ void lattice_scatter_kernel(const float* __restrict__ acids,
                                       const int*   __restrict__ idx,
                                       const int*   __restrict__ mask,
                                       float*       __restrict__ out) {
    int t = blockIdx.x * blockDim.x + threadIdx.x;   // 0 .. B*N-1
    if (t >= PB * PN) return;
    if (mask[t] == 0) return;        // masked-off acids scatter 0 -> no-op under add
    float v = acids[t];
    int b = t >> 6;                  // t / N  (N == 64)
    int i0 = idx[3 * t + 0] + (PN - 1);
    int i1 = idx[3 * t + 1] + (PN - 1);
    int i2 = idx[3 * t + 2] + (PN - 1);
    size_t off = ((((size_t)b * PL + i0) * PL) + i1) * PL + i2;
    atomicAdd(out + off, v);         // device-scope; handles index collisions
}

extern "C" void kernel_launch(void* const* d_in, const int* in_sizes, int n_in,
                              void* d_out, int out_size, void* d_ws, size_t ws_size,
                              hipStream_t stream) {
    const float* acids = (const float*)d_in[0];   // (B,N) f32
    const int*   idx   = (const int*)  d_in[1];   // (B,N,3) i32
    const int*   mask  = (const int*)  d_in[2];   // (B,N) bool -> i32 per harness
    float* out = (float*)d_out;

    // Zero the lattice: 8 coalesced float4 stores/thread, regular stores.
    constexpr long long PER_BLOCK = (long long)ZB * ZPT;              // 2048 v4
    int zgrid = (int)((TOTAL_V4 + PER_BLOCK - 1) / PER_BLOCK);        // 8002
    lattice_zero_kernel<<<zgrid, ZB, 0, stream>>>((float4*)out);

    // Scatter-add the 2048 masked values (stream-ordered after the zero).
    constexpr int total = PB * PN;   // 2048
    lattice_scatter_kernel<<<(total + 255) / 256, 256, 0, stream>>>(acids, idx, mask, out);
}